// Round 8
// baseline (1357.385 us; speedup 1.0000x reference)
//
#include <hip/hip_runtime.h>
#include <math.h>

// Problem constants (fixed by setup_inputs)
#define BB 64
#define CC 512
#define CR 32
#define HW 3136
#define HW4 784                    // HW/4 float4 per plane
#define NBLK 2048                  // exactly co-resident: 8 blocks/CU x 256 CU
#define NCNT 64                    // barrier tree counters
#define ARRV (NBLK / NCNT)         // 32 arrivals per counter

typedef float f32x4 __attribute__((ext_vector_type(4)));

// ---------------------------------------------------------------------------
// Persistent single-dispatch SE. Each wave holds 4 full planes in registers
// (4 x 13 f32x4 = 208 VGPRs) across a device-wide barrier, so x is read from
// HBM exactly once and never re-fetched. s crosses XCDs via agent-scope
// atomics (coherent point), NOT via per-block L2 writebacks (the R2 mistake).
// __launch_bounds__(256,8): VGPR cap 256 -> 8 blocks/CU -> all 2048 resident.
// ---------------------------------------------------------------------------
__global__ __launch_bounds__(256, 8) void se_persistent(
    const float* __restrict__ x,
    const float* __restrict__ w1, const float* __restrict__ b1,
    const float* __restrict__ w2, const float* __restrict__ b2,
    float* __restrict__ out,
    int* cnt, float* s)
{
    const int t    = threadIdx.x;
    const int wave = t >> 6;
    const int lane = t & 63;
    const int blk  = blockIdx.x;
    const int p0   = blk * 16 + wave * 4;     // this wave's first plane
    const int b    = blk >> 5;                // batch (uniform per block)
    const bool tl  = (lane < 16);             // tail: 784 = 12*64 + 16

    // ---- Phase 1: pull 4 planes into registers (52 NT loads in flight),
    //      pool-reduce each, publish s via agent-scope stores. ----
    f32x4 v[4][12];
    f32x4 vt[4];
    #pragma unroll
    for (int q = 0; q < 4; ++q) {
        const f32x4* x4 = reinterpret_cast<const f32x4*>(x) + (size_t)(p0 + q) * HW4;
        #pragma unroll
        for (int k = 0; k < 12; ++k)
            v[q][k] = __builtin_nontemporal_load(&x4[lane + 64 * k]);
        vt[q] = (f32x4){0.f, 0.f, 0.f, 0.f};
        if (tl) vt[q] = __builtin_nontemporal_load(&x4[768 + lane]);
    }
    #pragma unroll
    for (int q = 0; q < 4; ++q) {
        f32x4 a = vt[q];
        #pragma unroll
        for (int k = 0; k < 12; ++k) a += v[q][k];
        float acc = (a.x + a.y) + (a.z + a.w);
        #pragma unroll
        for (int off = 32; off > 0; off >>= 1)
            acc += __shfl_down(acc, off, 64);
        if (lane == 0)
            __hip_atomic_store(&s[p0 + q], acc * (1.0f / (float)HW),
                               __ATOMIC_RELAXED, __HIP_MEMORY_SCOPE_AGENT);
    }

    // ---- Phase 2: device-wide barrier. Arrive: 1 release-add per block on a
    //      64-way counter tree. Wait: wave 0's lanes spin (bounded). ----
    __syncthreads();                          // drains all waves' s-stores
    if (t == 0)
        __hip_atomic_fetch_add(&cnt[blk & (NCNT - 1)], 1,
                               __ATOMIC_RELEASE, __HIP_MEMORY_SCOPE_AGENT);
    if (t < NCNT) {
        int spins = 0;
        while (__hip_atomic_load(&cnt[t], __ATOMIC_ACQUIRE,
                                 __HIP_MEMORY_SCOPE_AGENT) < ARRV &&
               spins < (1 << 20)) {
            ++spins;
            __builtin_amdgcn_s_sleep(8);
        }
    }
    __syncthreads();

    // ---- Phase 3: FC for this block's batch (agent-scope s reads). ----
    __shared__ float s_sh[CC];
    __shared__ float h_sh[CR];
    s_sh[t]       = __hip_atomic_load(&s[b * CC + t],
                                      __ATOMIC_RELAXED, __HIP_MEMORY_SCOPE_AGENT);
    s_sh[t + 256] = __hip_atomic_load(&s[b * CC + t + 256],
                                      __ATOMIC_RELAXED, __HIP_MEMORY_SCOPE_AGENT);
    __syncthreads();
    {
        const int r = t >> 3, part = t & 7;
        const float* wr = w1 + r * CC;
        float ha = 0.0f;
        #pragma unroll
        for (int k = 0; k < CC / 8; ++k) {
            const int c = part + 8 * k;
            ha = fmaf(s_sh[c], wr[c], ha);
        }
        ha += __shfl_down(ha, 4, 8);
        ha += __shfl_down(ha, 2, 8);
        ha += __shfl_down(ha, 1, 8);
        if (part == 0) h_sh[r] = fmaxf(ha + b1[r], 0.0f);
    }
    __syncthreads();

    // ---- Phase 4: gate each plane, scale registers, NT store. ----
    #pragma unroll
    for (int q = 0; q < 4; ++q) {
        const int c = (p0 + q) & (CC - 1);
        float a2 = b2[c];
        const float* w2r = w2 + c * CR;
        #pragma unroll
        for (int r = 0; r < CR; ++r)
            a2 = fmaf(h_sh[r], w2r[r], a2);
        const float gv = 1.0f / (1.0f + expf(-a2));

        f32x4* o4 = reinterpret_cast<f32x4*>(out) + (size_t)(p0 + q) * HW4;
        #pragma unroll
        for (int k = 0; k < 12; ++k)
            __builtin_nontemporal_store(v[q][k] * gv, &o4[lane + 64 * k]);
        if (tl)
            __builtin_nontemporal_store(vt[q] * gv, &o4[768 + lane]);
    }
}

// ---------------------------------------------------------------------------
extern "C" void kernel_launch(void* const* d_in, const int* in_sizes, int n_in,
                              void* d_out, int out_size, void* d_ws, size_t ws_size,
                              hipStream_t stream) {
    const float* x  = (const float*)d_in[0];
    const float* w1 = (const float*)d_in[1];
    const float* b1 = (const float*)d_in[2];
    const float* w2 = (const float*)d_in[3];
    const float* b2 = (const float*)d_in[4];
    float* out = (float*)d_out;

    int*   cnt = (int*)d_ws;                  // [64] barrier counters
    float* s   = (float*)d_ws + 64;           // [BB*CC] squeeze means

    // counters must be zero every call (graph replays don't re-poison ws)
    hipMemsetAsync(cnt, 0, NCNT * sizeof(int), stream);

    se_persistent<<<NBLK, 256, 0, stream>>>(x, w1, b1, w2, b2, out, cnt, s);
}

// Round 9
// 225.034 us; speedup vs baseline: 6.0319x; 6.0319x over previous
//
#include <hip/hip_runtime.h>
#include <math.h>

// Problem constants (fixed by setup_inputs)
#define BB 64
#define CC 512
#define CR 32
#define HW 3136
#define HW4 784                    // HW/4 float4 per plane
#define GROUP_B 16                 // batches per group (102.8 MB chunk: chunk + out-stream < L3)
#define NGROUP (BB / GROUP_B)      // 4
#define PLANES_G (GROUP_B * CC)    // 8192 planes per group
#define WPB 4                      // waves per block (256 threads)

typedef float f32x4 __attribute__((ext_vector_type(4)));

// ---------------------------------------------------------------------------
// Kernel 1: global average pool. One WAVE per plane (identical to R7-204us).
// ---------------------------------------------------------------------------
__global__ __launch_bounds__(256) void se_pool(const float* __restrict__ x,
                                               float* __restrict__ s, int group) {
    const int wave = threadIdx.x >> 6;
    const int lane = threadIdx.x & 63;
    const int p = group * PLANES_G + blockIdx.x * WPB + wave;
    const f32x4* x4 = reinterpret_cast<const f32x4*>(x) + (size_t)p * HW4;

    float acc = 0.0f;
    for (int i = lane; i < HW4; i += 64) {
        f32x4 v = x4[i];
        acc += (v.x + v.y) + (v.z + v.w);
    }
    #pragma unroll
    for (int off = 32; off > 0; off >>= 1)
        acc += __shfl_down(acc, off, 64);
    if (lane == 0)
        s[p] = acc * (1.0f / (float)HW);
}

// ---------------------------------------------------------------------------
// Kernel 2: FC bottleneck + sigmoid gate (identical to R7-204us).
// ---------------------------------------------------------------------------
__global__ __launch_bounds__(256) void se_fc(
    const float* __restrict__ s,
    const float* __restrict__ w1, const float* __restrict__ b1,
    const float* __restrict__ w2, const float* __restrict__ b2,
    float* __restrict__ g, int group)
{
    const int b = group * GROUP_B + blockIdx.x;
    const int t = threadIdx.x;
    __shared__ float s_sh[CC];
    __shared__ float h_sh[CR];

    s_sh[t]       = s[b * CC + t];
    s_sh[t + 256] = s[b * CC + t + 256];
    __syncthreads();

    const int r = t >> 3, part = t & 7;
    const float* wr = w1 + r * CC;
    float ha = 0.0f;
    #pragma unroll
    for (int k = 0; k < CC / 8; ++k) {
        const int c = part + 8 * k;
        ha = fmaf(s_sh[c], wr[c], ha);
    }
    ha += __shfl_down(ha, 4, 8);
    ha += __shfl_down(ha, 2, 8);
    ha += __shfl_down(ha, 1, 8);
    if (part == 0) h_sh[r] = fmaxf(ha + b1[r], 0.0f);
    __syncthreads();

    #pragma unroll
    for (int j = 0; j < 2; ++j) {
        const int c2 = t + j * 256;
        float a2 = b2[c2];
        const float* w2r = w2 + c2 * CR;
        #pragma unroll
        for (int rr = 0; rr < CR; ++rr)
            a2 = fmaf(h_sh[rr], w2r[rr], a2);
        g[b * CC + c2] = 1.0f / (1.0f + expf(-a2));
    }
}

// ---------------------------------------------------------------------------
// Kernel 3: scale. One WAVE per plane; load whole plane into registers (one
// vmcnt wait point), multiply, then all NT stores (identical to R7-204us).
// ---------------------------------------------------------------------------
__global__ __launch_bounds__(256) void se_scale(
    const float* __restrict__ x, const float* __restrict__ g,
    float* __restrict__ out, int group)
{
    const int wave = threadIdx.x >> 6;
    const int lane = threadIdx.x & 63;
    const int p = group * PLANES_G + blockIdx.x * WPB + wave;
    const float gv = g[p];                         // same addr across wave -> broadcast
    const size_t base = (size_t)p * HW4;
    const f32x4* x4 = reinterpret_cast<const f32x4*>(x) + base;
    f32x4*       o4 = reinterpret_cast<f32x4*>(out) + base;

    f32x4 v[12];
    #pragma unroll
    for (int k = 0; k < 12; ++k)                   // 12 independent loads
        v[k] = x4[lane + 64 * k];
    f32x4 vt;
    const bool tail = (lane < 16);                 // 784 = 12*64 + 16
    if (tail) vt = x4[768 + lane];

    #pragma unroll
    for (int k = 0; k < 12; ++k)
        v[k] *= gv;
    if (tail) vt *= gv;

    #pragma unroll
    for (int k = 0; k < 12; ++k)
        __builtin_nontemporal_store(v[k], &o4[lane + 64 * k]);
    if (tail) __builtin_nontemporal_store(vt, &o4[768 + lane]);
}

// ---------------------------------------------------------------------------
extern "C" void kernel_launch(void* const* d_in, const int* in_sizes, int n_in,
                              void* d_out, int out_size, void* d_ws, size_t ws_size,
                              hipStream_t stream) {
    const float* x  = (const float*)d_in[0];
    const float* w1 = (const float*)d_in[1];
    const float* b1 = (const float*)d_in[2];
    const float* w2 = (const float*)d_in[3];
    const float* b2 = (const float*)d_in[4];
    float* out = (float*)d_out;

    float* s = (float*)d_ws;                       // [BB*CC] = 128 KB
    float* g = s + BB * CC;                        // [BB*CC] = 128 KB

    for (int grp = 0; grp < NGROUP; ++grp) {
        se_pool <<<PLANES_G / WPB, 256, 0, stream>>>(x, s, grp);
        se_fc   <<<GROUP_B, 256, 0, stream>>>(s, w1, b1, w2, b2, g, grp);
        se_scale<<<PLANES_G / WPB, 256, 0, stream>>>(x, g, out, grp);
    }
}

// Round 10
// 206.103 us; speedup vs baseline: 6.5860x; 1.0919x over previous
//
#include <hip/hip_runtime.h>
#include <math.h>

// Problem constants (fixed by setup_inputs)
#define BB 64
#define CC 512
#define CR 32
#define HW 3136
#define HW4 784                    // HW/4 float4 per plane
#define GROUP_B 32                 // batches per L3-resident group (205.6 MB < 256 MB L3)
#define NGROUP (BB / GROUP_B)      // 2
#define PLANES_G (GROUP_B * CC)    // 16384 planes per group
#define WPB 4                      // waves per block (256 threads)

typedef float f32x4 __attribute__((ext_vector_type(4)));

// ---------------------------------------------------------------------------
// Kernel 1: global average pool. One WAVE per plane. CHANGED vs R7: batch all
// 12+tail plane loads into registers (one vmcnt wait point) before summing —
// removes the scalar-accumulator load-latency chain. Normal loads (populate
// L3 for the scale pass).
// ---------------------------------------------------------------------------
__global__ __launch_bounds__(256) void se_pool(const float* __restrict__ x,
                                               float* __restrict__ s, int group) {
    const int wave = threadIdx.x >> 6;
    const int lane = threadIdx.x & 63;
    const int p = group * PLANES_G + blockIdx.x * WPB + wave;
    const f32x4* x4 = reinterpret_cast<const f32x4*>(x) + (size_t)p * HW4;

    f32x4 v[12];
    #pragma unroll
    for (int k = 0; k < 12; ++k)                   // 12 independent loads
        v[k] = x4[lane + 64 * k];
    f32x4 vt = (f32x4){0.f, 0.f, 0.f, 0.f};
    if (lane < 16) vt = x4[768 + lane];            // tail: 784 = 12*64 + 16

    // vector tree sum: 12 regs + tail -> 1 reg
    #pragma unroll
    for (int k = 0; k < 6; ++k) v[k] += v[k + 6];
    #pragma unroll
    for (int k = 0; k < 3; ++k) v[k] += v[k + 3];
    f32x4 a = (v[0] + v[1]) + (v[2] + vt);
    float acc = (a.x + a.y) + (a.z + a.w);

    #pragma unroll
    for (int off = 32; off > 0; off >>= 1)
        acc += __shfl_down(acc, off, 64);
    if (lane == 0)
        s[p] = acc * (1.0f / (float)HW);
}

// ---------------------------------------------------------------------------
// Kernel 2: FC bottleneck + sigmoid gate (identical to R7-204us).
// ---------------------------------------------------------------------------
__global__ __launch_bounds__(256) void se_fc(
    const float* __restrict__ s,
    const float* __restrict__ w1, const float* __restrict__ b1,
    const float* __restrict__ w2, const float* __restrict__ b2,
    float* __restrict__ g, int group)
{
    const int b = group * GROUP_B + blockIdx.x;
    const int t = threadIdx.x;
    __shared__ float s_sh[CC];
    __shared__ float h_sh[CR];

    s_sh[t]       = s[b * CC + t];
    s_sh[t + 256] = s[b * CC + t + 256];
    __syncthreads();

    const int r = t >> 3, part = t & 7;
    const float* wr = w1 + r * CC;
    float ha = 0.0f;
    #pragma unroll
    for (int k = 0; k < CC / 8; ++k) {
        const int c = part + 8 * k;
        ha = fmaf(s_sh[c], wr[c], ha);
    }
    ha += __shfl_down(ha, 4, 8);
    ha += __shfl_down(ha, 2, 8);
    ha += __shfl_down(ha, 1, 8);
    if (part == 0) h_sh[r] = fmaxf(ha + b1[r], 0.0f);
    __syncthreads();

    #pragma unroll
    for (int j = 0; j < 2; ++j) {
        const int c2 = t + j * 256;
        float a2 = b2[c2];
        const float* w2r = w2 + c2 * CR;
        #pragma unroll
        for (int rr = 0; rr < CR; ++rr)
            a2 = fmaf(h_sh[rr], w2r[rr], a2);
        g[b * CC + c2] = 1.0f / (1.0f + expf(-a2));
    }
}

// ---------------------------------------------------------------------------
// Kernel 3: scale (identical to R7-204us). Load whole plane into registers,
// multiply, then all NT stores.
// ---------------------------------------------------------------------------
__global__ __launch_bounds__(256) void se_scale(
    const float* __restrict__ x, const float* __restrict__ g,
    float* __restrict__ out, int group)
{
    const int wave = threadIdx.x >> 6;
    const int lane = threadIdx.x & 63;
    const int p = group * PLANES_G + blockIdx.x * WPB + wave;
    const float gv = g[p];                         // same addr across wave -> broadcast
    const size_t base = (size_t)p * HW4;
    const f32x4* x4 = reinterpret_cast<const f32x4*>(x) + base;
    f32x4*       o4 = reinterpret_cast<f32x4*>(out) + base;

    f32x4 v[12];
    #pragma unroll
    for (int k = 0; k < 12; ++k)                   // 12 independent loads
        v[k] = x4[lane + 64 * k];
    f32x4 vt;
    const bool tail = (lane < 16);                 // 784 = 12*64 + 16
    if (tail) vt = x4[768 + lane];

    #pragma unroll
    for (int k = 0; k < 12; ++k)
        v[k] *= gv;
    if (tail) vt *= gv;

    #pragma unroll
    for (int k = 0; k < 12; ++k)
        __builtin_nontemporal_store(v[k], &o4[lane + 64 * k]);
    if (tail) __builtin_nontemporal_store(vt, &o4[768 + lane]);
}

// ---------------------------------------------------------------------------
extern "C" void kernel_launch(void* const* d_in, const int* in_sizes, int n_in,
                              void* d_out, int out_size, void* d_ws, size_t ws_size,
                              hipStream_t stream) {
    const float* x  = (const float*)d_in[0];
    const float* w1 = (const float*)d_in[1];
    const float* b1 = (const float*)d_in[2];
    const float* w2 = (const float*)d_in[3];
    const float* b2 = (const float*)d_in[4];
    float* out = (float*)d_out;

    float* s = (float*)d_ws;                       // [BB*CC] = 128 KB
    float* g = s + BB * CC;                        // [BB*CC] = 128 KB

    for (int grp = 0; grp < NGROUP; ++grp) {
        se_pool <<<PLANES_G / WPB, 256, 0, stream>>>(x, s, grp);
        se_fc   <<<GROUP_B, 256, 0, stream>>>(s, w1, b1, w2, b2, g, grp);
        se_scale<<<PLANES_G / WPB, 256, 0, stream>>>(x, g, out, grp);
    }
}